// Round 1
// baseline (646.682 us; speedup 1.0000x reference)
//
#include <hip/hip_runtime.h>
#include <math.h>
#include <stdint.h>

typedef unsigned short u16;
typedef __bf16 bf16x8 __attribute__((ext_vector_type(8)));
typedef float f32x4 __attribute__((ext_vector_type(4)));

constexpr int Bb = 2, Ss = 2048, Dd = 1024, Hh = 16, Hd = 64, Win = 256;
constexpr int Mtot = Bb * Ss;   // 4096

// ---------- helpers ----------
__device__ __forceinline__ u16 f2bf(float f) {
    uint32_t u = __float_as_uint(f);
    u += 0x7fff + ((u >> 16) & 1);   // RNE
    return (u16)(u >> 16);
}

__device__ __forceinline__ void gload16(const void* g, void* l) {
    __builtin_amdgcn_global_load_lds(
        (const __attribute__((address_space(1))) uint32_t*)g,
        (__attribute__((address_space(3))) uint32_t*)l, 16, 0, 0);
}

// ---------- fp32 -> bf16 convert (vectorized) ----------
__global__ void cvt4(const float* __restrict__ s, u16* __restrict__ d, int n4) {
    int i = blockIdx.x * blockDim.x + threadIdx.x;
    if (i >= n4) return;
    float4 v = reinterpret_cast<const float4*>(s)[i];
    ushort4 o;
    o.x = f2bf(v.x); o.y = f2bf(v.y); o.z = f2bf(v.z); o.w = f2bf(v.w);
    reinterpret_cast<ushort4*>(d)[i] = o;
}

// ---------- RoPE tables: cos/sin[s][d], freq index = d mod 32 ----------
__global__ void rope_tables(float* __restrict__ ct, float* __restrict__ st) {
    int i = blockIdx.x * blockDim.x + threadIdx.x;   // over Ss*64
    if (i >= Ss * 64) return;
    int s = i >> 6, d = i & 63;
    float invf = powf(10000.0f, -(float)(d & 31) / 32.0f);
    float ang = (float)s * invf;
    ct[i] = cosf(ang);
    st[i] = sinf(ang);
}

// ---------- RoPE apply, in-place on fp32 [B*H][S][64]; y-dim picks Q/K ----------
__global__ void rope_apply(float* __restrict__ Q, float* __restrict__ K,
                           const float* __restrict__ ct, const float* __restrict__ st) {
    float* P = blockIdx.y ? K : Q;
    int i = blockIdx.x * blockDim.x + threadIdx.x;   // over B*H*S*32 (pairs)
    int pr = i & 31;
    int s = (i >> 5) & (Ss - 1);
    size_t base = (size_t)(i >> 5) * 64;             // (bh*S + s)*64
    int d0 = pr * 2, d1 = d0 + 1;
    float a = P[base + d0], b = P[base + d1];
    float c0 = ct[s * 64 + d0], c1 = ct[s * 64 + d1];
    float s0 = st[s * 64 + d0], s1 = st[s * 64 + d1];
    P[base + d0] = a * c0 - b * s0;
    P[base + d1] = b * c1 + a * s1;
}

// ---------- bf16 MFMA GEMM: C[m][n] = sum_k A[m][k] * Bw[n][k] ----------
// 128x128 tile, BK=32, 4 waves (2x2), 4x4 x mfma_f32_16x16x32_bf16 per wave.
// MODE 0: write QKV fp32 into [B][H][S][64].  MODE 1: write fp32 [M][N].
template <int MODE>
__global__ __launch_bounds__(256) void gemm_k(
    const u16* __restrict__ A,
    const u16* __restrict__ B0, const u16* __restrict__ B1, const u16* __restrict__ B2,
    float* __restrict__ C0, float* __restrict__ C1, float* __restrict__ C2,
    int M, int N, int Kd)
{
    const u16* Bw = (blockIdx.z == 0) ? B0 : (blockIdx.z == 1) ? B1 : B2;
    float* C = (blockIdx.z == 0) ? C0 : (blockIdx.z == 1) ? C1 : C2;

    __shared__ u16 sA[128 * 32];
    __shared__ u16 sB[128 * 32];

    const int t = threadIdx.x, l = t & 63, w = t >> 6;
    const int wm = w >> 1, wn = w & 1;
    const int m0 = blockIdx.x * 128, n0 = blockIdx.y * 128;
    const int lr = l & 15, kg = l >> 4;

    f32x4 acc[4][4] = {};

    for (int k0 = 0; k0 < Kd; k0 += 32) {
        __syncthreads();
#pragma unroll
        for (int p = 0; p < 2; ++p) {
            int i = p * 256 + t;
            int r = i >> 2, c = (i & 3) * 8;
            gload16(A  + (size_t)(m0 + r) * Kd + k0 + c, &sA[i * 8]);
            gload16(Bw + (size_t)(n0 + r) * Kd + k0 + c, &sB[i * 8]);
        }
        __syncthreads();

        bf16x8 af[4], bfr[4];
#pragma unroll
        for (int im = 0; im < 4; ++im)
            af[im] = *reinterpret_cast<const bf16x8*>(&sA[(wm * 64 + im * 16 + lr) * 32 + kg * 8]);
#pragma unroll
        for (int in = 0; in < 4; ++in)
            bfr[in] = *reinterpret_cast<const bf16x8*>(&sB[(wn * 64 + in * 16 + lr) * 32 + kg * 8]);
#pragma unroll
        for (int im = 0; im < 4; ++im)
#pragma unroll
            for (int in = 0; in < 4; ++in)
                acc[im][in] = __builtin_amdgcn_mfma_f32_16x16x32_bf16(af[im], bfr[in], acc[im][in], 0, 0, 0);
    }

#pragma unroll
    for (int im = 0; im < 4; ++im) {
#pragma unroll
        for (int in = 0; in < 4; ++in) {
#pragma unroll
            for (int j = 0; j < 4; ++j) {
                int row = m0 + wm * 64 + im * 16 + kg * 4 + j;
                int col = n0 + wn * 64 + in * 16 + lr;
                float v = acc[im][in][j];
                if (MODE == 0) {
                    int b = row >> 11, s = row & 2047;
                    int h = col >> 6, d = col & 63;
                    C[(((size_t)(b * 16 + h)) * 2048 + s) * 64 + d] = v;
                } else {
                    C[(size_t)row * N + col] = v;
                }
            }
        }
    }
}

// ---------- sliding-window causal attention: one wave per query row ----------
// Q,K,V fp32 [B*H][S][64]; output bf16 [B][S][D] (ready for the Wo GEMM)
__global__ __launch_bounds__(256) void attn_kernel(
    const float* __restrict__ Q, const float* __restrict__ K,
    const float* __restrict__ V, u16* __restrict__ O)
{
    __shared__ float sq[4][64];
    __shared__ float sp[4][256];

    const int t = threadIdx.x, l = t & 63, w = t >> 6;
    const int gw = blockIdx.x * 4 + w;        // global wave = query index over B*H*S
    const int q = gw & (Ss - 1);
    const int bh = gw >> 11;

    const float* Kbh = K + (size_t)bh * Ss * Hd;
    const float* Vbh = V + (size_t)bh * Ss * Hd;

    float qv = Q[((size_t)bh * Ss + q) * Hd + l];
    sq[w][l] = qv;  // per-wave LDS, in-order DS ops: no barrier needed

    int k0 = q - (Win - 1); if (k0 < 0) k0 = 0;
    const int cnt = q - k0 + 1;

    float sc[4];
#pragma unroll
    for (int tt = 0; tt < 4; ++tt) {
        int j = l + tt * 64;
        float s = -INFINITY;
        if (j < cnt) {
            const float* kr = Kbh + (size_t)(k0 + j) * Hd;
            float acc = 0.f;
#pragma unroll
            for (int d4 = 0; d4 < 16; ++d4) {
                float4 kv = reinterpret_cast<const float4*>(kr)[d4];
                float4 qq = reinterpret_cast<const float4*>(sq[w])[d4];
                acc += qq.x * kv.x + qq.y * kv.y + qq.z * kv.z + qq.w * kv.w;
            }
            s = acc * 0.125f;
        }
        sc[tt] = s;
    }

    float m = fmaxf(fmaxf(sc[0], sc[1]), fmaxf(sc[2], sc[3]));
#pragma unroll
    for (int off = 32; off; off >>= 1) m = fmaxf(m, __shfl_xor(m, off));

    float sum = 0.f;
#pragma unroll
    for (int tt = 0; tt < 4; ++tt) {
        float p = (sc[tt] == -INFINITY) ? 0.f : __expf(sc[tt] - m);
        sp[w][l + tt * 64] = p;
        sum += p;
    }
#pragma unroll
    for (int off = 32; off; off >>= 1) sum += __shfl_xor(sum, off);
    float rsum = 1.0f / sum;

    // PV: lane = output dim, coalesced V reads
    float y = 0.f;
    int j = 0;
    for (; j + 4 <= cnt; j += 4) {
        float4 p4 = *reinterpret_cast<const float4*>(&sp[w][j]);
        const float* vb = Vbh + (size_t)(k0 + j) * Hd + l;
        y += p4.x * vb[0];
        y += p4.y * vb[64];
        y += p4.z * vb[128];
        y += p4.w * vb[192];
    }
    for (; j < cnt; ++j) y += sp[w][j] * Vbh[(size_t)(k0 + j) * Hd + l];
    y *= rsum;

    int b = bh >> 4, h = bh & 15;
    O[((size_t)(b * Ss + q)) * Dd + h * 64 + l] = f2bf(y);
}

// ---------- launch ----------
extern "C" void kernel_launch(void* const* d_in, const int* in_sizes, int n_in,
                              void* d_out, int out_size, void* d_ws, size_t ws_size,
                              hipStream_t stream) {
    const float* x  = (const float*)d_in[0];
    const float* Wq = (const float*)d_in[1];
    const float* Wk = (const float*)d_in[2];
    const float* Wv = (const float*)d_in[3];
    const float* Wo = (const float*)d_in[4];
    float* out = (float*)d_out;

    char* ws = (char*)d_ws;
    size_t off = 0;
    auto carve = [&](size_t bytes) -> char* {
        char* p = ws + off;
        off += (bytes + 255) & ~(size_t)255;
        return p;
    };
    float* cosT = (float*)carve((size_t)Ss * 64 * 4);
    float* sinT = (float*)carve((size_t)Ss * 64 * 4);
    u16* xb  = (u16*)carve((size_t)Mtot * Dd * 2);
    u16* wqb = (u16*)carve((size_t)Dd * Dd * 2);
    u16* wkb = (u16*)carve((size_t)Dd * Dd * 2);
    u16* wvb = (u16*)carve((size_t)Dd * Dd * 2);
    u16* wob = (u16*)carve((size_t)Dd * Dd * 2);
    float* Qf = (float*)carve((size_t)Mtot * Dd * 4);
    float* Kf = (float*)carve((size_t)Mtot * Dd * 4);
    float* Vf = (float*)carve((size_t)Mtot * Dd * 4);
    u16* attb = (u16*)carve((size_t)Mtot * Dd * 2);

    const int nx4 = Mtot * Dd / 4, nw4 = Dd * Dd / 4;
    cvt4<<<nx4 / 256, 256, 0, stream>>>(x, xb, nx4);
    cvt4<<<nw4 / 256, 256, 0, stream>>>(Wq, wqb, nw4);
    cvt4<<<nw4 / 256, 256, 0, stream>>>(Wk, wkb, nw4);
    cvt4<<<nw4 / 256, 256, 0, stream>>>(Wv, wvb, nw4);
    cvt4<<<nw4 / 256, 256, 0, stream>>>(Wo, wob, nw4);
    rope_tables<<<(Ss * 64) / 256, 256, 0, stream>>>(cosT, sinT);

    gemm_k<0><<<dim3(Mtot / 128, Dd / 128, 3), 256, 0, stream>>>(
        xb, wqb, wkb, wvb, Qf, Kf, Vf, Mtot, Dd, Dd);

    rope_apply<<<dim3((Bb * Hh * Ss * 32) / 256, 2), 256, 0, stream>>>(Qf, Kf, cosT, sinT);

    attn_kernel<<<(Bb * Hh * Ss) / 4, 256, 0, stream>>>(Qf, Kf, Vf, attb);

    gemm_k<1><<<dim3(Mtot / 128, Dd / 128, 1), 256, 0, stream>>>(
        attb, wob, wob, wob, out, out, out, Mtot, Dd, Dd);
}

// Round 2
// 136.310 us; speedup vs baseline: 4.7442x; 4.7442x over previous
//
#include <hip/hip_runtime.h>
#include <math.h>
#include <stdint.h>

typedef unsigned short u16;
typedef __bf16 bf16x8 __attribute__((ext_vector_type(8)));
typedef float f32x4 __attribute__((ext_vector_type(4)));
typedef u16 u16x8 __attribute__((ext_vector_type(8)));

constexpr int Bb = 2, Ss = 2048, Dd = 1024, Hh = 16, Hd = 64, Win = 256;
constexpr int Mtot = Bb * Ss;   // 4096

// ---------- helpers ----------
__device__ __forceinline__ u16 f2bf(float f) {
    uint32_t u = __float_as_uint(f);
    u += 0x7fff + ((u >> 16) & 1);   // RNE
    return (u16)(u >> 16);
}

__device__ __forceinline__ void gload16(const void* g, void* l) {
    __builtin_amdgcn_global_load_lds(
        (const __attribute__((address_space(1))) uint32_t*)g,
        (__attribute__((address_space(3))) uint32_t*)l, 16, 0, 0);
}

// ---------- fp32 -> bf16 convert (vectorized) ----------
__global__ void cvt4(const float* __restrict__ s, u16* __restrict__ d, int n4) {
    int i = blockIdx.x * blockDim.x + threadIdx.x;
    if (i >= n4) return;
    float4 v = reinterpret_cast<const float4*>(s)[i];
    ushort4 o;
    o.x = f2bf(v.x); o.y = f2bf(v.y); o.z = f2bf(v.z); o.w = f2bf(v.w);
    reinterpret_cast<ushort4*>(d)[i] = o;
}

// ---------- RoPE tables: cos/sin[s][d], freq index = d mod 32 ----------
__global__ void rope_tables(float* __restrict__ ct, float* __restrict__ st) {
    int i = blockIdx.x * blockDim.x + threadIdx.x;   // over Ss*64
    if (i >= Ss * 64) return;
    int s = i >> 6, d = i & 63;
    float invf = powf(10000.0f, -(float)(d & 31) / 32.0f);
    float ang = (float)s * invf;
    ct[i] = cosf(ang);
    st[i] = sinf(ang);
}

// ---------- RoPE (Q,K) + bf16 cast (Q,K,V): fp32 [bh][s][64] -> bf16 ----------
__global__ void ropecvt(const float* __restrict__ Qf, const float* __restrict__ Kf,
                        const float* __restrict__ Vf,
                        u16* __restrict__ Qb, u16* __restrict__ Kb, u16* __restrict__ Vb,
                        const float* __restrict__ ct, const float* __restrict__ st) {
    const int which = blockIdx.y;
    const float* src = (which == 0) ? Qf : (which == 1) ? Kf : Vf;
    u16* dst = (which == 0) ? Qb : (which == 1) ? Kb : Vb;
    int i = blockIdx.x * blockDim.x + threadIdx.x;   // pair index over B*H*S*32
    int pr = i & 31;
    int s = (i >> 5) & (Ss - 1);
    size_t base = (size_t)(i >> 5) * 64;
    int d0 = pr * 2;
    float2 ab = *reinterpret_cast<const float2*>(src + base + d0);
    u16 o0, o1;
    if (which < 2) {
        float c0 = ct[s * 64 + d0], c1 = ct[s * 64 + d0 + 1];
        float s0 = st[s * 64 + d0], s1 = st[s * 64 + d0 + 1];
        o0 = f2bf(ab.x * c0 - ab.y * s0);
        o1 = f2bf(ab.y * c1 + ab.x * s1);
    } else {
        o0 = f2bf(ab.x);
        o1 = f2bf(ab.y);
    }
    ushort2 o; o.x = o0; o.y = o1;
    *reinterpret_cast<ushort2*>(dst + base + d0) = o;
}

// ---------- bf16 MFMA GEMM: C[m][n] = sum_k A[m][k] * Bw[n][k] ----------
template <int MODE>
__global__ __launch_bounds__(256) void gemm_k(
    const u16* __restrict__ A,
    const u16* __restrict__ B0, const u16* __restrict__ B1, const u16* __restrict__ B2,
    float* __restrict__ C0, float* __restrict__ C1, float* __restrict__ C2,
    int M, int N, int Kd)
{
    const u16* Bw = (blockIdx.z == 0) ? B0 : (blockIdx.z == 1) ? B1 : B2;
    float* C = (blockIdx.z == 0) ? C0 : (blockIdx.z == 1) ? C1 : C2;

    __shared__ u16 sA[128 * 32];
    __shared__ u16 sB[128 * 32];

    const int t = threadIdx.x, l = t & 63, w = t >> 6;
    const int wm = w >> 1, wn = w & 1;
    const int m0 = blockIdx.x * 128, n0 = blockIdx.y * 128;
    const int lr = l & 15, kg = l >> 4;

    f32x4 acc[4][4] = {};

    for (int k0 = 0; k0 < Kd; k0 += 32) {
        __syncthreads();
#pragma unroll
        for (int p = 0; p < 2; ++p) {
            int i = p * 256 + t;
            int r = i >> 2, c = (i & 3) * 8;
            gload16(A  + (size_t)(m0 + r) * Kd + k0 + c, &sA[i * 8]);
            gload16(Bw + (size_t)(n0 + r) * Kd + k0 + c, &sB[i * 8]);
        }
        __syncthreads();

        bf16x8 af[4], bfr[4];
#pragma unroll
        for (int im = 0; im < 4; ++im)
            af[im] = *reinterpret_cast<const bf16x8*>(&sA[(wm * 64 + im * 16 + lr) * 32 + kg * 8]);
#pragma unroll
        for (int in = 0; in < 4; ++in)
            bfr[in] = *reinterpret_cast<const bf16x8*>(&sB[(wn * 64 + in * 16 + lr) * 32 + kg * 8]);
#pragma unroll
        for (int im = 0; im < 4; ++im)
#pragma unroll
            for (int in = 0; in < 4; ++in)
                acc[im][in] = __builtin_amdgcn_mfma_f32_16x16x32_bf16(af[im], bfr[in], acc[im][in], 0, 0, 0);
    }

#pragma unroll
    for (int im = 0; im < 4; ++im) {
#pragma unroll
        for (int in = 0; in < 4; ++in) {
#pragma unroll
            for (int j = 0; j < 4; ++j) {
                int row = m0 + wm * 64 + im * 16 + kg * 4 + j;
                int col = n0 + wn * 64 + in * 16 + lr;
                float v = acc[im][in][j];
                if (MODE == 0) {
                    int b = row >> 11, s = row & 2047;
                    int h = col >> 6, d = col & 63;
                    C[(((size_t)(b * 16 + h)) * 2048 + s) * 64 + d] = v;
                } else {
                    C[(size_t)row * N + col] = v;
                }
            }
        }
    }
}

// ---------- MFMA flash attention, window=256 ----------
// Qb,Kb,Vb bf16 [bh][s][64] (rope applied to Q,K). O bf16 [B][S][D].
// Workgroup: 4 waves, one (bh, 64-query tile). Wave w owns q rows w*16..w*16+15.
// LDS tiles swizzled: element (r,c) at byte (r*128 + c*2) ^ ((r&7)<<4).
__global__ __launch_bounds__(256) void fattn(
    const u16* __restrict__ Qb, const u16* __restrict__ Kb,
    const u16* __restrict__ Vb, u16* __restrict__ O)
{
    __shared__ u16 sQ[64 * 64];
    __shared__ u16 sK[64 * 64];
    __shared__ u16 sVT[64 * 64];
    __shared__ u16 sP[4][16 * 64];

    const int t = threadIdx.x, l = t & 63, w = t >> 6;
    const int lo = l & 15, hi = l >> 4;
    const int qt = blockIdx.x, bh = blockIdx.y;
    const int q0 = qt * 64;

    // ---- stage Q tile (linear LDS dest, pre-swizzled global src) ----
    const char* Qg = (const char*)(Qb + ((size_t)bh * Ss + q0) * 64);
#pragma unroll
    for (int p = 0; p < 2; ++p) {
        uint32_t x = (uint32_t)(w * 2 + p) * 1024 + l * 16;
        uint32_t sx = x ^ (((x >> 7) & 7) << 4);
        gload16(Qg + sx, (char*)sQ + x);
    }
    __syncthreads();

    // Q A-fragments, held in registers for the whole kernel
    bf16x8 qf[2];
#pragma unroll
    for (int ck = 0; ck < 2; ++ck) {
        uint32_t b = (uint32_t)(w * 16 + lo) * 128 + ck * 64 + hi * 16;
        b ^= ((lo & 7) << 4);
        qf[ck] = *reinterpret_cast<const bf16x8*>((const char*)sQ + b);
    }

    f32x4 o[4] = {};
    float mj[4], lj[4];
#pragma unroll
    for (int j = 0; j < 4; ++j) { mj[j] = -1e30f; lj[j] = 0.f; }

    const int jt0 = (qt >= 4) ? qt - 4 : 0;
    for (int jt = jt0; jt <= qt; ++jt) {
        __syncthreads();   // all waves done reading sK/sVT of prev tile
        // ---- stage K tile ----
        const char* Kg = (const char*)(Kb + ((size_t)bh * Ss + jt * 64) * 64);
#pragma unroll
        for (int p = 0; p < 2; ++p) {
            uint32_t x = (uint32_t)(w * 2 + p) * 1024 + l * 16;
            uint32_t sx = x ^ (((x >> 7) & 7) << 4);
            gload16(Kg + sx, (char*)sK + x);
        }
        // ---- stage V transposed (reg path) ----
        const u16* Vg = Vb + ((size_t)bh * Ss + jt * 64) * 64;
#pragma unroll
        for (int p = 0; p < 2; ++p) {
            int c = p * 256 + t;
            int kr = c >> 3, dc = (c & 7) * 8;
            u16x8 vv = *reinterpret_cast<const u16x8*>(Vg + (size_t)kr * 64 + dc);
#pragma unroll
            for (int ii = 0; ii < 8; ++ii) {
                int d = dc + ii;
                uint32_t b = ((uint32_t)d * 128 + kr * 2) ^ (((uint32_t)(d & 7)) << 4);
                *(u16*)((char*)sVT + b) = vv[ii];
            }
        }
        __syncthreads();

        // ---- QK^T: scores[q][k] ----
        f32x4 s4[4] = {};
#pragma unroll
        for (int ck = 0; ck < 2; ++ck) {
#pragma unroll
            for (int nb = 0; nb < 4; ++nb) {
                uint32_t b = (uint32_t)(nb * 16 + lo) * 128 + ck * 64 + hi * 16;
                b ^= ((lo & 7) << 4);
                bf16x8 kf = *reinterpret_cast<const bf16x8*>((const char*)sK + b);
                s4[nb] = __builtin_amdgcn_mfma_f32_16x16x32_bf16(qf[ck], kf, s4[nb], 0, 0, 0);
            }
        }

        // ---- scale + window/causal mask ----
        const int qbase = q0 + w * 16 + hi * 4;
#pragma unroll
        for (int nb = 0; nb < 4; ++nb) {
            int k = jt * 64 + nb * 16 + lo;
#pragma unroll
            for (int j = 0; j < 4; ++j) {
                int q = qbase + j;
                float v = s4[nb][j] * 0.125f;
                bool ok = (k <= q) && (q - k < Win);
                s4[nb][j] = ok ? v : -1e30f;
            }
        }

        // ---- online softmax (k spread over 16 lo-lanes x 4 regs) ----
#pragma unroll
        for (int j = 0; j < 4; ++j) {
            float tm = fmaxf(fmaxf(s4[0][j], s4[1][j]), fmaxf(s4[2][j], s4[3][j]));
            tm = fmaxf(tm, __shfl_xor(tm, 1));
            tm = fmaxf(tm, __shfl_xor(tm, 2));
            tm = fmaxf(tm, __shfl_xor(tm, 4));
            tm = fmaxf(tm, __shfl_xor(tm, 8));
            float nm = fmaxf(fmaxf(mj[j], tm), -1e20f);  // -1e20 guard: all-masked rows
            float sc = __expf(mj[j] - nm);
            mj[j] = nm;
            lj[j] *= sc;
#pragma unroll
            for (int nb = 0; nb < 4; ++nb) o[nb][j] *= sc;
            float ps = 0.f;
#pragma unroll
            for (int nb = 0; nb < 4; ++nb) {
                float p = __expf(s4[nb][j] - nm);
                ps += p;
                s4[nb][j] = p;
            }
            lj[j] += ps;   // lane-partial over lo; reduced once at the end
        }

        // ---- P -> per-wave LDS (bf16, swizzled [16][64]); same-wave DS is in-order ----
#pragma unroll
        for (int nb = 0; nb < 4; ++nb) {
#pragma unroll
            for (int j = 0; j < 4; ++j) {
                int r = hi * 4 + j;
                uint32_t b = ((uint32_t)r * 128 + (nb * 16 + lo) * 2) ^ (((uint32_t)(r & 7)) << 4);
                *(u16*)((char*)&sP[w][0] + b) = f2bf(s4[nb][j]);
            }
        }

        // ---- PV: O += P @ V ----
#pragma unroll
        for (int ck = 0; ck < 2; ++ck) {
            uint32_t bp = ((uint32_t)lo * 128 + ck * 64 + hi * 16) ^ (((uint32_t)(lo & 7)) << 4);
            bf16x8 pa = *reinterpret_cast<const bf16x8*>((const char*)&sP[w][0] + bp);
#pragma unroll
            for (int nb = 0; nb < 4; ++nb) {
                uint32_t bb = ((uint32_t)(nb * 16 + lo) * 128 + ck * 64 + hi * 16) ^ (((uint32_t)(lo & 7)) << 4);
                bf16x8 vf = *reinterpret_cast<const bf16x8*>((const char*)sVT + bb);
                o[nb] = __builtin_amdgcn_mfma_f32_16x16x32_bf16(pa, vf, o[nb], 0, 0, 0);
            }
        }
    }

    // ---- finalize: reduce l over lo lanes, normalize, store ----
#pragma unroll
    for (int j = 0; j < 4; ++j) {
        float s = lj[j];
        s += __shfl_xor(s, 1);
        s += __shfl_xor(s, 2);
        s += __shfl_xor(s, 4);
        s += __shfl_xor(s, 8);
        lj[j] = 1.0f / s;
    }
    const int bq = bh >> 4, h = bh & 15;
#pragma unroll
    for (int nb = 0; nb < 4; ++nb) {
#pragma unroll
        for (int j = 0; j < 4; ++j) {
            int q = q0 + w * 16 + hi * 4 + j;
            int d = nb * 16 + lo;
            O[((size_t)(bq * Ss + q)) * Dd + h * 64 + d] = f2bf(o[nb][j] * lj[j]);
        }
    }
}

// ---------- launch ----------
extern "C" void kernel_launch(void* const* d_in, const int* in_sizes, int n_in,
                              void* d_out, int out_size, void* d_ws, size_t ws_size,
                              hipStream_t stream) {
    const float* x  = (const float*)d_in[0];
    const float* Wq = (const float*)d_in[1];
    const float* Wk = (const float*)d_in[2];
    const float* Wv = (const float*)d_in[3];
    const float* Wo = (const float*)d_in[4];
    float* out = (float*)d_out;

    char* ws = (char*)d_ws;
    size_t off = 0;
    auto carve = [&](size_t bytes) -> char* {
        char* p = ws + off;
        off += (bytes + 255) & ~(size_t)255;
        return p;
    };
    float* cosT = (float*)carve((size_t)Ss * 64 * 4);
    float* sinT = (float*)carve((size_t)Ss * 64 * 4);
    u16* xb  = (u16*)carve((size_t)Mtot * Dd * 2);
    u16* wqb = (u16*)carve((size_t)Dd * Dd * 2);
    u16* wkb = (u16*)carve((size_t)Dd * Dd * 2);
    u16* wvb = (u16*)carve((size_t)Dd * Dd * 2);
    u16* wob = (u16*)carve((size_t)Dd * Dd * 2);
    float* Qf = (float*)carve((size_t)Mtot * Dd * 4);
    float* Kf = (float*)carve((size_t)Mtot * Dd * 4);
    float* Vf = (float*)carve((size_t)Mtot * Dd * 4);
    u16* Qbb = (u16*)carve((size_t)Mtot * Dd * 2);
    u16* Kbb = (u16*)carve((size_t)Mtot * Dd * 2);
    u16* Vbb = (u16*)carve((size_t)Mtot * Dd * 2);
    u16* attb = (u16*)Qf;   // reuse Qf region: fp32 Q dead after ropecvt

    const int nx4 = Mtot * Dd / 4, nw4 = Dd * Dd / 4;
    cvt4<<<nx4 / 256, 256, 0, stream>>>(x, xb, nx4);
    cvt4<<<nw4 / 256, 256, 0, stream>>>(Wq, wqb, nw4);
    cvt4<<<nw4 / 256, 256, 0, stream>>>(Wk, wkb, nw4);
    cvt4<<<nw4 / 256, 256, 0, stream>>>(Wv, wvb, nw4);
    cvt4<<<nw4 / 256, 256, 0, stream>>>(Wo, wob, nw4);
    rope_tables<<<(Ss * 64) / 256, 256, 0, stream>>>(cosT, sinT);

    gemm_k<0><<<dim3(Mtot / 128, Dd / 128, 3), 256, 0, stream>>>(
        xb, wqb, wkb, wvb, Qf, Kf, Vf, Mtot, Dd, Dd);

    ropecvt<<<dim3((Bb * Hh * Ss * 32) / 256, 3), 256, 0, stream>>>(
        Qf, Kf, Vf, Qbb, Kbb, Vbb, cosT, sinT);

    fattn<<<dim3(Ss / 64, Bb * Hh), 256, 0, stream>>>(Qbb, Kbb, Vbb, attb);

    gemm_k<1><<<dim3(Mtot / 128, Dd / 128, 1), 256, 0, stream>>>(
        attb, wob, wob, wob, out, out, out, Mtot, Dd, Dd);
}

// Round 3
// 123.486 us; speedup vs baseline: 5.2369x; 1.1039x over previous
//
#include <hip/hip_runtime.h>
#include <math.h>
#include <stdint.h>

typedef unsigned short u16;
typedef __bf16 bf16x8 __attribute__((ext_vector_type(8)));
typedef float f32x4 __attribute__((ext_vector_type(4)));
typedef u16 u16x8 __attribute__((ext_vector_type(8)));

constexpr int Bb = 2, Ss = 2048, Dd = 1024, Hh = 16, Hd = 64, Win = 256;
constexpr int Mtot = Bb * Ss;   // 4096

// ---------- helpers ----------
__device__ __forceinline__ u16 f2bf(float f) {
    uint32_t u = __float_as_uint(f);
    u += 0x7fff + ((u >> 16) & 1);   // RNE
    return (u16)(u >> 16);
}

__device__ __forceinline__ void gload16(const void* g, void* l) {
    __builtin_amdgcn_global_load_lds(
        (const __attribute__((address_space(1))) uint32_t*)g,
        (__attribute__((address_space(3))) uint32_t*)l, 16, 0, 0);
}

// ---------- fp32 -> bf16 convert (vectorized) ----------
__global__ void cvt4(const float* __restrict__ s, u16* __restrict__ d, int n4) {
    int i = blockIdx.x * blockDim.x + threadIdx.x;
    if (i >= n4) return;
    float4 v = reinterpret_cast<const float4*>(s)[i];
    ushort4 o;
    o.x = f2bf(v.x); o.y = f2bf(v.y); o.z = f2bf(v.z); o.w = f2bf(v.w);
    reinterpret_cast<ushort4*>(d)[i] = o;
}

// 4 weight matrices in one dispatch (blockIdx.y selects)
__global__ void cvt4w(const float* __restrict__ s0, const float* __restrict__ s1,
                      const float* __restrict__ s2, const float* __restrict__ s3,
                      u16* __restrict__ d0, u16* __restrict__ d1,
                      u16* __restrict__ d2, u16* __restrict__ d3, int n4) {
    const int wsel = blockIdx.y;
    const float* s = (wsel == 0) ? s0 : (wsel == 1) ? s1 : (wsel == 2) ? s2 : s3;
    u16* d = (wsel == 0) ? d0 : (wsel == 1) ? d1 : (wsel == 2) ? d2 : d3;
    int i = blockIdx.x * blockDim.x + threadIdx.x;
    if (i >= n4) return;
    float4 v = reinterpret_cast<const float4*>(s)[i];
    ushort4 o;
    o.x = f2bf(v.x); o.y = f2bf(v.y); o.z = f2bf(v.z); o.w = f2bf(v.w);
    reinterpret_cast<ushort4*>(d)[i] = o;
}

// ---------- RoPE tables: cos/sin[s][d], freq index = d mod 32 ----------
__global__ void rope_tables(float* __restrict__ ct, float* __restrict__ st) {
    int i = blockIdx.x * blockDim.x + threadIdx.x;   // over Ss*64
    if (i >= Ss * 64) return;
    int s = i >> 6, d = i & 63;
    float invf = powf(10000.0f, -(float)(d & 31) / 32.0f);
    float ang = (float)s * invf;
    ct[i] = cosf(ang);
    st[i] = sinf(ang);
}

// ---------- bf16 MFMA GEMM: C[m][n] = sum_k A[m][k] * Bw[n][k] ----------
// 128x128 tile, BK=32, 4 waves (2x2), 4x4 x mfma_f32_16x16x32_bf16 per wave.
// MODE 0: fused RoPE (z<2) + bf16 cast, write [bh][s][64].
// MODE 1: write fp32 [M][N].
template <int MODE>
__global__ __launch_bounds__(256) void gemm_k(
    const u16* __restrict__ A,
    const u16* __restrict__ B0, const u16* __restrict__ B1, const u16* __restrict__ B2,
    void* __restrict__ C0, void* __restrict__ C1, void* __restrict__ C2,
    const float* __restrict__ ct, const float* __restrict__ st,
    int M, int N, int Kd)
{
    const u16* Bw = (blockIdx.z == 0) ? B0 : (blockIdx.z == 1) ? B1 : B2;
    void* C = (blockIdx.z == 0) ? C0 : (blockIdx.z == 1) ? C1 : C2;

    __shared__ u16 sA[128 * 32];
    __shared__ u16 sB[128 * 32];

    const int t = threadIdx.x, l = t & 63, w = t >> 6;
    const int wm = w >> 1, wn = w & 1;
    const int m0 = blockIdx.x * 128, n0 = blockIdx.y * 128;
    const int lr = l & 15, kg = l >> 4;

    f32x4 acc[4][4] = {};

    for (int k0 = 0; k0 < Kd; k0 += 32) {
        __syncthreads();
#pragma unroll
        for (int p = 0; p < 2; ++p) {
            int i = p * 256 + t;
            int r = i >> 2, c = (i & 3) * 8;
            gload16(A  + (size_t)(m0 + r) * Kd + k0 + c, &sA[i * 8]);
            gload16(Bw + (size_t)(n0 + r) * Kd + k0 + c, &sB[i * 8]);
        }
        __syncthreads();

        bf16x8 af[4], bfr[4];
#pragma unroll
        for (int im = 0; im < 4; ++im)
            af[im] = *reinterpret_cast<const bf16x8*>(&sA[(wm * 64 + im * 16 + lr) * 32 + kg * 8]);
#pragma unroll
        for (int in = 0; in < 4; ++in)
            bfr[in] = *reinterpret_cast<const bf16x8*>(&sB[(wn * 64 + in * 16 + lr) * 32 + kg * 8]);
#pragma unroll
        for (int im = 0; im < 4; ++im)
#pragma unroll
            for (int in = 0; in < 4; ++in)
                acc[im][in] = __builtin_amdgcn_mfma_f32_16x16x32_bf16(af[im], bfr[in], acc[im][in], 0, 0, 0);
    }

    const bool dorope = (MODE == 0) && (blockIdx.z < 2);
#pragma unroll
    for (int im = 0; im < 4; ++im) {
#pragma unroll
        for (int in = 0; in < 4; ++in) {
#pragma unroll
            for (int j = 0; j < 4; ++j) {
                int row = m0 + wm * 64 + im * 16 + kg * 4 + j;
                int col = n0 + wn * 64 + in * 16 + lr;
                float v = acc[im][in][j];
                if (MODE == 0) {
                    // partner for rotate-half: col^1 lives in lane l^1, same regs
                    float vp = __shfl_xor(v, 1);
                    int b = row >> 11, s = row & 2047;
                    int h = col >> 6, d = col & 63;
                    float outv = v;
                    if (dorope) {
                        float c = ct[s * 64 + d], sn = st[s * 64 + d];
                        outv = (col & 1) ? (v * c + vp * sn) : (v * c - vp * sn);
                    }
                    ((u16*)C)[(((size_t)(b * 16 + h)) * 2048 + s) * 64 + d] = f2bf(outv);
                } else {
                    ((float*)C)[(size_t)row * N + col] = v;
                }
            }
        }
    }
}

// ---------- MFMA flash attention, window=256 ----------
// Qb,Kb,Vb bf16 [bh][s][64] (rope already applied to Q,K). O bf16 [B][S][D].
// Workgroup: 4 waves, one (bh, 64-query tile). Wave w owns q rows w*16..w*16+15.
// LDS tiles swizzled: element (r,c) at byte (r*128 + c*2) ^ ((r&7)<<4).
__global__ __launch_bounds__(256) void fattn(
    const u16* __restrict__ Qb, const u16* __restrict__ Kb,
    const u16* __restrict__ Vb, u16* __restrict__ O)
{
    __shared__ u16 sQ[64 * 64];
    __shared__ u16 sK[64 * 64];
    __shared__ u16 sVT[64 * 64];
    __shared__ u16 sP[4][16 * 64];

    const int t = threadIdx.x, l = t & 63, w = t >> 6;
    const int lo = l & 15, hi = l >> 4;
    const int qt = blockIdx.x, bh = blockIdx.y;
    const int q0 = qt * 64;

    // ---- stage Q tile (linear LDS dest, pre-swizzled global src) ----
    const char* Qg = (const char*)(Qb + ((size_t)bh * Ss + q0) * 64);
#pragma unroll
    for (int p = 0; p < 2; ++p) {
        uint32_t x = (uint32_t)(w * 2 + p) * 1024 + l * 16;
        uint32_t sx = x ^ (((x >> 7) & 7) << 4);
        gload16(Qg + sx, (char*)sQ + x);
    }
    __syncthreads();

    // Q A-fragments, held in registers for the whole kernel
    bf16x8 qf[2];
#pragma unroll
    for (int ck = 0; ck < 2; ++ck) {
        uint32_t b = (uint32_t)(w * 16 + lo) * 128 + ck * 64 + hi * 16;
        b ^= ((lo & 7) << 4);
        qf[ck] = *reinterpret_cast<const bf16x8*>((const char*)sQ + b);
    }

    f32x4 o[4] = {};
    float mj[4], lj[4];
#pragma unroll
    for (int j = 0; j < 4; ++j) { mj[j] = -1e30f; lj[j] = 0.f; }

    const int jt0 = (qt >= 4) ? qt - 4 : 0;
    for (int jt = jt0; jt <= qt; ++jt) {
        __syncthreads();   // all waves done reading sK/sVT of prev tile
        // ---- stage K tile ----
        const char* Kg = (const char*)(Kb + ((size_t)bh * Ss + jt * 64) * 64);
#pragma unroll
        for (int p = 0; p < 2; ++p) {
            uint32_t x = (uint32_t)(w * 2 + p) * 1024 + l * 16;
            uint32_t sx = x ^ (((x >> 7) & 7) << 4);
            gload16(Kg + sx, (char*)sK + x);
        }
        // ---- stage V transposed (reg path) ----
        const u16* Vg = Vb + ((size_t)bh * Ss + jt * 64) * 64;
#pragma unroll
        for (int p = 0; p < 2; ++p) {
            int c = p * 256 + t;
            int kr = c >> 3, dc = (c & 7) * 8;
            u16x8 vv = *reinterpret_cast<const u16x8*>(Vg + (size_t)kr * 64 + dc);
#pragma unroll
            for (int ii = 0; ii < 8; ++ii) {
                int d = dc + ii;
                uint32_t b = ((uint32_t)d * 128 + kr * 2) ^ (((uint32_t)(d & 7)) << 4);
                *(u16*)((char*)sVT + b) = vv[ii];
            }
        }
        __syncthreads();

        // ---- QK^T: scores[q][k] ----
        f32x4 s4[4] = {};
#pragma unroll
        for (int ck = 0; ck < 2; ++ck) {
#pragma unroll
            for (int nb = 0; nb < 4; ++nb) {
                uint32_t b = (uint32_t)(nb * 16 + lo) * 128 + ck * 64 + hi * 16;
                b ^= ((lo & 7) << 4);
                bf16x8 kf = *reinterpret_cast<const bf16x8*>((const char*)sK + b);
                s4[nb] = __builtin_amdgcn_mfma_f32_16x16x32_bf16(qf[ck], kf, s4[nb], 0, 0, 0);
            }
        }

        // ---- scale + window/causal mask ----
        const int qbase = q0 + w * 16 + hi * 4;
#pragma unroll
        for (int nb = 0; nb < 4; ++nb) {
            int k = jt * 64 + nb * 16 + lo;
#pragma unroll
            for (int j = 0; j < 4; ++j) {
                int q = qbase + j;
                float v = s4[nb][j] * 0.125f;
                bool ok = (k <= q) && (q - k < Win);
                s4[nb][j] = ok ? v : -1e30f;
            }
        }

        // ---- online softmax (k spread over 16 lo-lanes x 4 regs) ----
#pragma unroll
        for (int j = 0; j < 4; ++j) {
            float tm = fmaxf(fmaxf(s4[0][j], s4[1][j]), fmaxf(s4[2][j], s4[3][j]));
            tm = fmaxf(tm, __shfl_xor(tm, 1));
            tm = fmaxf(tm, __shfl_xor(tm, 2));
            tm = fmaxf(tm, __shfl_xor(tm, 4));
            tm = fmaxf(tm, __shfl_xor(tm, 8));
            float nm = fmaxf(fmaxf(mj[j], tm), -1e20f);  // -1e20 guard: all-masked rows
            float sc = __expf(mj[j] - nm);
            mj[j] = nm;
            lj[j] *= sc;
#pragma unroll
            for (int nb = 0; nb < 4; ++nb) o[nb][j] *= sc;
            float ps = 0.f;
#pragma unroll
            for (int nb = 0; nb < 4; ++nb) {
                float p = __expf(s4[nb][j] - nm);
                ps += p;
                s4[nb][j] = p;
            }
            lj[j] += ps;   // lane-partial over lo; reduced once at the end
        }

        // ---- P -> per-wave LDS (bf16, swizzled [16][64]); same-wave DS is in-order ----
#pragma unroll
        for (int nb = 0; nb < 4; ++nb) {
#pragma unroll
            for (int j = 0; j < 4; ++j) {
                int r = hi * 4 + j;
                uint32_t b = ((uint32_t)r * 128 + (nb * 16 + lo) * 2) ^ (((uint32_t)(r & 7)) << 4);
                *(u16*)((char*)&sP[w][0] + b) = f2bf(s4[nb][j]);
            }
        }

        // ---- PV: O += P @ V ----
#pragma unroll
        for (int ck = 0; ck < 2; ++ck) {
            uint32_t bp = ((uint32_t)lo * 128 + ck * 64 + hi * 16) ^ (((uint32_t)(lo & 7)) << 4);
            bf16x8 pa = *reinterpret_cast<const bf16x8*>((const char*)&sP[w][0] + bp);
#pragma unroll
            for (int nb = 0; nb < 4; ++nb) {
                uint32_t bb = ((uint32_t)(nb * 16 + lo) * 128 + ck * 64 + hi * 16) ^ (((uint32_t)(lo & 7)) << 4);
                bf16x8 vf = *reinterpret_cast<const bf16x8*>((const char*)sVT + bb);
                o[nb] = __builtin_amdgcn_mfma_f32_16x16x32_bf16(pa, vf, o[nb], 0, 0, 0);
            }
        }
    }

    // ---- finalize: reduce l over lo lanes, normalize, store ----
#pragma unroll
    for (int j = 0; j < 4; ++j) {
        float s = lj[j];
        s += __shfl_xor(s, 1);
        s += __shfl_xor(s, 2);
        s += __shfl_xor(s, 4);
        s += __shfl_xor(s, 8);
        lj[j] = 1.0f / s;
    }
    const int bq = bh >> 4, h = bh & 15;
#pragma unroll
    for (int nb = 0; nb < 4; ++nb) {
#pragma unroll
        for (int j = 0; j < 4; ++j) {
            int q = q0 + w * 16 + hi * 4 + j;
            int d = nb * 16 + lo;
            O[((size_t)(bq * Ss + q)) * Dd + h * 64 + d] = f2bf(o[nb][j] * lj[j]);
        }
    }
}

// ---------- launch ----------
extern "C" void kernel_launch(void* const* d_in, const int* in_sizes, int n_in,
                              void* d_out, int out_size, void* d_ws, size_t ws_size,
                              hipStream_t stream) {
    const float* x  = (const float*)d_in[0];
    const float* Wq = (const float*)d_in[1];
    const float* Wk = (const float*)d_in[2];
    const float* Wv = (const float*)d_in[3];
    const float* Wo = (const float*)d_in[4];
    float* out = (float*)d_out;

    char* ws = (char*)d_ws;
    size_t off = 0;
    auto carve = [&](size_t bytes) -> char* {
        char* p = ws + off;
        off += (bytes + 255) & ~(size_t)255;
        return p;
    };
    float* cosT = (float*)carve((size_t)Ss * 64 * 4);
    float* sinT = (float*)carve((size_t)Ss * 64 * 4);
    u16* xb  = (u16*)carve((size_t)Mtot * Dd * 2);
    u16* wqb = (u16*)carve((size_t)Dd * Dd * 2);
    u16* wkb = (u16*)carve((size_t)Dd * Dd * 2);
    u16* wvb = (u16*)carve((size_t)Dd * Dd * 2);
    u16* wob = (u16*)carve((size_t)Dd * Dd * 2);
    u16* Qbb = (u16*)carve((size_t)Mtot * Dd * 2);
    u16* Kbb = (u16*)carve((size_t)Mtot * Dd * 2);
    u16* Vbb = (u16*)carve((size_t)Mtot * Dd * 2);
    u16* attb = (u16*)carve((size_t)Mtot * Dd * 2);

    const int nx4 = Mtot * Dd / 4, nw4 = Dd * Dd / 4;
    cvt4<<<nx4 / 256, 256, 0, stream>>>(x, xb, nx4);
    cvt4w<<<dim3(nw4 / 256, 4), 256, 0, stream>>>(Wq, Wk, Wv, Wo, wqb, wkb, wvb, wob, nw4);
    rope_tables<<<(Ss * 64) / 256, 256, 0, stream>>>(cosT, sinT);

    gemm_k<0><<<dim3(Mtot / 128, Dd / 128, 3), 256, 0, stream>>>(
        xb, wqb, wkb, wvb, Qbb, Kbb, Vbb, cosT, sinT, Mtot, Dd, Dd);

    fattn<<<dim3(Ss / 64, Bb * Hh), 256, 0, stream>>>(Qbb, Kbb, Vbb, attb);

    gemm_k<1><<<dim3(Mtot / 128, Dd / 128, 1), 256, 0, stream>>>(
        attb, wob, wob, wob, out, out, out, nullptr, nullptr, Mtot, Dd, Dd);
}